// Round 3
// baseline (435.717 us; speedup 1.0000x reference)
//
#include <hip/hip_runtime.h>

// CostVolume: out[b,h,w,i0*9+j0] = mean_c( prv[b,h,w,c] * nxt[b,h+i0-4,w+j0-4,c] )
// B=16, H=W=128, C=192, r=4, d=9, 81 offsets. fp32 in/out, bf16 MFMA internally.
//
// v3: v2's reg-staged prefetch was defeated by the register allocator (VGPR=64 <
// acc+afrag+staging), re-exposing ~900cy/chunk. Replace staging with
// global_load_lds direct-to-LDS (fp32, linear layout as gll requires), 2x32KiB
// double buffer, prefetch depth 2 kept alive across a raw s_barrier (only
// lgkmcnt(0), no vmcnt drain). Bank conflicts on the 128B pixel stride fixed via
// pre-swizzled global source + XOR-swizzled ds_read (rule #21: both sides).
// fp32->bf16 conversion moves into the MFMA loop (v_cvt_pk_bf16_f32). OOB halo
// zeroing: each wave zeroes its own staged slots (edge blocks only).
// XCD swizzle: 512 contiguous blocks (2 images) per XCD for L2 halo reuse.

typedef __attribute__((ext_vector_type(8))) short short8;
typedef __attribute__((ext_vector_type(4))) float float4v;

#define HH 128
#define WW 128
#define CC 192
#define BUFB 32768                 // one staging buffer: 256 px * 32ch * 4B
#define GROWP 17                   // epilogue G stride (floats)
#define GWAVE (144 * GROWP)

static __device__ __forceinline__ unsigned int pk2(float lo, float hi) {
    unsigned int r;
    asm("v_cvt_pk_bf16_f32 %0, %1, %2" : "=v"(r) : "v"(lo), "v"(hi));
    return r;
}

static __device__ __forceinline__ short8 cvt8pk(const float* __restrict__ p) {
    float4v f0 = *reinterpret_cast<const float4v*>(p);
    float4v f1 = *reinterpret_cast<const float4v*>(p + 4);
    union { unsigned int u[4]; short8 s; } r;
    r.u[0] = pk2(f0[0], f0[1]);
    r.u[1] = pk2(f0[2], f0[3]);
    r.u[2] = pk2(f1[0], f1[1]);
    r.u[3] = pk2(f1[2], f1[3]);
    return r.s;
}

// async global->LDS, 16B/lane; LDS dest = wave-uniform base + lane*16 (HW rule)
static __device__ __forceinline__ void gll16(const float* g, void* l) {
    __builtin_amdgcn_global_load_lds(
        (const __attribute__((address_space(1))) unsigned int*)g,
        (__attribute__((address_space(3))) unsigned int*)l,
        16, 0, 0);
}

__global__ __launch_bounds__(256, 2) void costvol_kernel(
    const float* __restrict__ prv,
    const float* __restrict__ nxt,
    float* __restrict__ out)
{
    const int tid  = threadIdx.x;        // 0..255
    const int lane = tid & 63;
    const int wv   = tid >> 6;           // wave 0..3
    const int m    = lane & 15;
    const int q    = lane >> 4;
    const int wr   = wv >> 1, wc = wv & 1;

    // XCD-aware swizzle: 4096 blocks, 8 XCDs, 512 contiguous (=2 images) each
    int bid = blockIdx.x + (blockIdx.y << 4) + (blockIdx.z << 8);
    bid = (bid & 7) * 512 + (bid >> 3);
    const int wt = bid & 15, ht = (bid >> 4) & 15, b = bid >> 8;
    const int h0 = ht * 8, w0 = wt * 8;

    const float* nxt_b = nxt + (size_t)b * HH * WW * CC;
    const float* prv_b = prv + (size_t)b * HH * WW * CC;

    __shared__ alignas(16) unsigned char smem[2 * BUFB];

    // ---- staging geometry: pixel P = i*32 + u32 <-> halo (row=P>>4, col=P&15)
    // LDS is linear: slot of (P, group jg) at P*128 + jg*16 (= wv*1024 + lane*16
    // + i*4096 for this thread). Swizzle: this slot holds global group jg^(P&7),
    // so the thread LOADS group jg^(u32&7)  (u32&7 == P&7 for all i).
    const int u32 = tid >> 3;            // 0..31
    const int jg  = tid & 7;
    const int jsw = jg ^ (u32 & 7);
    const int hcol = u32 & 15;
    const int dpar = u32 >> 4;
    const int wwg = w0 - 4 + hcol;
    const bool okw = (wwg >= 0) && (wwg < WW);
    const int wcl = wwg < 0 ? 0 : (wwg > WW - 1 ? WW - 1 : wwg);

    const float* gp[8];
    unsigned okmask = 0;
#pragma unroll
    for (int i = 0; i < 8; ++i) {
        int hh = h0 - 4 + 2 * i + dpar;
        bool ok = okw && (hh >= 0) && (hh < HH);
        int hcl = hh < 0 ? 0 : (hh > HH - 1 ? HH - 1 : hh);
        gp[i] = nxt_b + ((size_t)(hcl * WW + wcl)) * CC + jsw * 4;
        okmask |= (unsigned)ok << i;
    }
    const bool edge = (wt == 0) | (wt == 15) | (ht == 0) | (ht == 15);

    // ---- B-fragment swizzled read offsets: data for (P, float q*8..q*8+7) at
    // (P*128 + q*32) ^ ((P&7)<<4)  and  that ^ 16.
    int roffA[9];
#pragma unroll
    for (int s = 0; s < 9; ++s) {
        int n  = s * 16 + m;
        int nr = n / 12, nc = n - nr * 12;
        int P  = (wr * 4 + nr) * 16 + (wc * 4 + nc);
        roffA[s] = (P * 128 + q * 32) ^ ((P & 7) << 4);
    }

    // ---- prv A-fragments in registers
    const int pr = m >> 2, pc = m & 3;
    const float* pbase =
        prv_b + ((size_t)(h0 + wr * 4 + pr) * WW + (w0 + wc * 4 + pc)) * CC + q * 8;
    short8 afrag[6];
#pragma unroll
    for (int kk = 0; kk < 6; ++kk) afrag[kk] = cvt8pk(pbase + kk * 32);

    unsigned char* ldsw = smem + wv * 1024;   // wave's gll base (lane*16 implicit)

    // ---- prologue: stage c0 -> buf0, c1 -> buf1
#pragma unroll
    for (int i = 0; i < 8; ++i) gll16(gp[i],      ldsw + 0 * BUFB + i * 4096);
#pragma unroll
    for (int i = 0; i < 8; ++i) gll16(gp[i] + 32, ldsw + 1 * BUFB + i * 4096);
    __syncthreads();                          // drains c0+c1 (vmcnt(0)+barrier)
    if (edge) {
#pragma unroll
        for (int i = 0; i < 8; ++i)
            if (!((okmask >> i) & 1u))
                *reinterpret_cast<float4v*>(smem + 0 * BUFB + i * 4096 + u32 * 128 + jg * 16)
                    = (float4v){0.f, 0.f, 0.f, 0.f};
    }
    asm volatile("s_waitcnt lgkmcnt(0)" ::: "memory");
    __builtin_amdgcn_sched_barrier(0);
    __builtin_amdgcn_s_barrier();             // publish zeroed buf0
    __builtin_amdgcn_sched_barrier(0);
    asm volatile("" ::: "memory");

    float4v acc[9];
#pragma unroll
    for (int s = 0; s < 9; ++s) acc[s] = (float4v){0.f, 0.f, 0.f, 0.f};

    // ---- main loop: 6 chunks of 32 channels
#pragma unroll
    for (int kk = 0; kk < 6; ++kk) {
        const int rb = kk & 1;
        short8 a = afrag[kk];
#pragma unroll
        for (int s = 0; s < 9; ++s) {
            float4v f0 = *reinterpret_cast<const float4v*>(smem + rb * BUFB + roffA[s]);
            float4v f1 = *reinterpret_cast<const float4v*>(smem + rb * BUFB + (roffA[s] ^ 16));
            union { unsigned int u[4]; short8 s8; } fr;
            fr.u[0] = pk2(f0[0], f0[1]);
            fr.u[1] = pk2(f0[2], f0[3]);
            fr.u[2] = pk2(f1[0], f1[1]);
            fr.u[3] = pk2(f1[2], f1[3]);
            acc[s] = __builtin_amdgcn_mfma_f32_16x16x32_bf16(a, fr.s8, acc[s], 0, 0, 0);
        }
        // A: all waves done reading buf rb; drains c(kk+1) (issued a chunk ago)
        __syncthreads();
        if (kk < 4) {
            // prefetch c(kk+2) into buf rb; stays in flight across barrier B
#pragma unroll
            for (int i = 0; i < 8; ++i)
                gll16(gp[i] + (kk + 2) * 32, ldsw + rb * BUFB + i * 4096);
        }
        if (kk < 5) {
            if (edge) {
                const int zb = (kk + 1) & 1;  // c(kk+1) landed (drained at A)
#pragma unroll
                for (int i = 0; i < 8; ++i)
                    if (!((okmask >> i) & 1u))
                        *reinterpret_cast<float4v*>(smem + zb * BUFB + i * 4096 + u32 * 128 + jg * 16)
                            = (float4v){0.f, 0.f, 0.f, 0.f};
            }
            asm volatile("s_waitcnt lgkmcnt(0)" ::: "memory");
            __builtin_amdgcn_sched_barrier(0);
            __builtin_amdgcn_s_barrier();     // B: buf[(kk+1)&1] published; prefetch alive
            __builtin_amdgcn_sched_barrier(0);
            asm volatile("" ::: "memory");
        }
    }

    // ---- epilogue: G through LDS (reuses staging space), coalesced stores
    float* Gf = reinterpret_cast<float*>(smem);
    const int gbase = wv * GWAVE;
#pragma unroll
    for (int s = 0; s < 9; ++s) {
        int col = s * 16 + m;
#pragma unroll
        for (int r = 0; r < 4; ++r)
            Gf[gbase + col * GROWP + q * 4 + r] = acc[s][r];
    }
    __syncthreads();

    const float scale = 1.0f / 192.0f;
#pragma unroll
    for (int t = 0; t < 21; ++t) {
        int f = t * 256 + tid;
        if (f < 5184) {
            int p   = f / 81;
            int k   = f - p * 81;
            int i0  = k / 9, j0 = k - i0 * 9;
            int pr8 = p >> 3, pc8 = p & 7;
            int gw  = ((pr8 >> 2) << 1) | (pc8 >> 2);
            int pi  = ((pr8 & 3) << 2) | (pc8 & 3);
            int col = ((pr8 & 3) + i0) * 12 + ((pc8 & 3) + j0);
            float v = Gf[gw * GWAVE + col * GROWP + pi] * scale;
            out[((size_t)(b * HH + (h0 + pr8)) * WW + (w0 + pc8)) * 81 + k] = v;
        }
    }
}

extern "C" void kernel_launch(void* const* d_in, const int* in_sizes, int n_in,
                              void* d_out, int out_size, void* d_ws, size_t ws_size,
                              hipStream_t stream) {
    const float* prv = (const float*)d_in[0];
    const float* nxt = (const float*)d_in[1];
    float* out = (float*)d_out;
    dim3 grid(WW / 8, HH / 8, 16);
    dim3 block(256);
    hipLaunchKernelGGL(costvol_kernel, grid, block, 0, stream, prv, nxt, out);
}